// Round 6
// baseline (627.363 us; speedup 1.0000x reference)
//
#include <hip/hip_runtime.h>

// cluster_layer: q[n,k] = (1/(1+||x_n - c_k||^2)) normalized over k  (alpha=1)
// N=1e6, D=64, K=20.
//
// History:
//  R2: 1 row/thread, divergent row loads, c via SGPR. 153 us, 19% BW.
//  R3: sched_barrier pin: +6 us (RA re-sank loads).
//  R4: persistent+NT: REGRESSION (WRITE 79->195 MB, occupancy 21%).
//  R5: v_pk_fma: +0 -> VALU-issue not binding.
//  R6: asm 16-deep vmcnt MLP: 128 us. Best so far; divergent addresses remain.
//  R7: one-shot 64KB global_load_lds staging: REGRESSION 174 us. Coalescing
//      fine (FETCH 152->125 MB) but the schedule is bursty: issue 64 loads ->
//      ALL waves drain at barrier -> 0.4 us compute -> exit/re-ramp. In-flight
//      bytes collapse between bursts; block lifetime ~23 us for 64 KB.
//  R8: continuous coalesced pipeline. Block = ONE wave, persistent, tile =
//      64 rows (15625 tiles exactly). Wave-private 2x16KB LDS double buffer:
//      { issue 16 DMA loads for tile t+G; s_waitcnt vmcnt(16)  (tile t landed,
//        t+G stays in flight); compute tile t }. No barriers at all (single
//      wave -> no cross-wave hazards; in-order issue makes buf reuse safe).
//      32 KB/block -> 5 blocks/CU; 80-160 KB continuously in flight per CU.
//      Staging keeps R7's pre-swizzled source <-> XOR-swizzled ds_read_b128
//      (bank-even); c via SGPR stream; csq via pre-kernel into d_ws.

#define NPTS  1000000
#define DIM   64
#define KCL   20
#define BLOCK 64
#define GRID  1280           // 5 single-wave blocks per CU (LDS-limited)
#define NTILES (NPTS / 64)   // 15625, exact

typedef float f32x4 __attribute__((ext_vector_type(4)));

__global__ void csq_kernel(const float* __restrict__ c, float* __restrict__ csq)
{
    const int k = threadIdx.x;
    if (k < KCL) {
        const f32x4* c4 = (const f32x4*)c + k * (DIM / 4);
        float s = 0.f;
        #pragma unroll
        for (int m = 0; m < DIM / 4; ++m) {
            const f32x4 v = c4[m];
            s += v.x * v.x + v.y * v.y + v.z * v.z + v.w * v.w;
        }
        csq[k] = s;
    }
}

__global__ __launch_bounds__(BLOCK, 2) void cluster_q_kernel(
    const float* __restrict__ x,
    const float* __restrict__ c,
    const float* __restrict__ csq,
    float* __restrict__ out)
{
    // 2 buffers x 64 rows x 256 B = 32 KB, private to this block's single wave.
    __shared__ f32x4 sX[2][64][DIM / 4];

    const int lane = threadIdx.x;          // block == one wave

    // Stage tile TILE (64 rows) into buffer BUF: 16 DMA instrs, each 1 KB
    // contiguous (4 consecutive rows). LDS dest linear (HW: base + lane*16);
    // source pre-swizzled so chunk p of LDS row r holds x[row][p ^ (r&7)].
#define STAGE(BUF, TILE)                                                      \
    {                                                                         \
        const size_t rb = (size_t)(TILE) * 64;                                \
        _Pragma("unroll")                                                     \
        for (int i = 0; i < 16; ++i) {                                        \
            const int r  = i * 4 + (lane >> 4);                               \
            const int ch = (lane & 15) ^ (r & 7);                             \
            const float* gsrc = x + (rb + r) * DIM + ch * 4;                  \
            __builtin_amdgcn_global_load_lds(                                 \
                (const __attribute__((address_space(1))) void*)gsrc,          \
                (__attribute__((address_space(3))) void*)&sX[BUF][i * 4][0],  \
                16, 0, 0);                                                    \
        }                                                                     \
    }

    int t = blockIdx.x;
    if (t >= NTILES) return;

    int cur = 0;
    STAGE(0, t)                            // prologue: tile t in flight

    for (; t < NTILES; t += GRID) {
        const int nxt = t + GRID;
        if (nxt < NTILES) {
            STAGE(cur ^ 1, nxt)            // 16 more loads in flight
            // Drain ONLY tile t's 16 loads (FIFO); keep tile nxt's in flight.
            asm volatile("s_waitcnt vmcnt(16)" ::: "memory");
        } else {
            asm volatile("s_waitcnt vmcnt(0)" ::: "memory");
        }
        __builtin_amdgcn_sched_barrier(0);

        // ---- compute 64 rows from sX[cur]; c via uniform SGPR stream ----
        float acc[KCL];
        #pragma unroll
        for (int k = 0; k < KCL; ++k) acc[k] = 0.f;
        float xsq = 0.f;

        #pragma unroll
        for (int m = 0; m < DIM / 4; ++m) {
            const f32x4 xv = sX[cur][lane][m ^ (lane & 7)];   // bank-even
            xsq += xv.x * xv.x + xv.y * xv.y + xv.z * xv.z + xv.w * xv.w;
            #pragma unroll
            for (int k = 0; k < KCL; ++k) {
                acc[k] += xv.x * c[k * DIM + 4 * m + 0]
                        + xv.y * c[k * DIM + 4 * m + 1]
                        + xv.z * c[k * DIM + 4 * m + 2]
                        + xv.w * c[k * DIM + 4 * m + 3];
            }
        }

        // epilogue: d2 -> q -> normalize -> 5 float4 stores
        float s = 0.f;
        #pragma unroll
        for (int k = 0; k < KCL; ++k) {
            const float d2 = xsq + csq[k] - 2.0f * acc[k];   // csq: s_load
            const float qq = __builtin_amdgcn_rcpf(1.0f + d2);
            acc[k] = qq;
            s += qq;
        }
        const float inv = __builtin_amdgcn_rcpf(s);

        const size_t row = (size_t)t * 64 + lane;
        f32x4* o4 = (f32x4*)(out + row * KCL);
        #pragma unroll
        for (int k = 0; k < KCL; k += 4) {
            f32x4 v;
            v.x = acc[k + 0] * inv;
            v.y = acc[k + 1] * inv;
            v.z = acc[k + 2] * inv;
            v.w = acc[k + 3] * inv;
            o4[k / 4] = v;                 // plain store: L2 merges lines
        }

        cur ^= 1;
    }
#undef STAGE
}

extern "C" void kernel_launch(void* const* d_in, const int* in_sizes, int n_in,
                              void* d_out, int out_size, void* d_ws, size_t ws_size,
                              hipStream_t stream) {
    const float* x = (const float*)d_in[0];   // (N, D) fp32
    const float* c = (const float*)d_in[1];   // (K, D) fp32
    float* out = (float*)d_out;               // (N, K) fp32
    float* csq = (float*)d_ws;                // 20 floats of workspace

    csq_kernel<<<1, 64, 0, stream>>>(c, csq);
    cluster_q_kernel<<<GRID, BLOCK, 0, stream>>>(x, c, csq, out);
}

// Round 7
// 442.972 us; speedup vs baseline: 1.4163x; 1.4163x over previous
//
#include <hip/hip_runtime.h>

// cluster_layer: q[n,k] = (1/(1+||x_n - c_k||^2)) normalized over k  (alpha=1)
// N=1e6, D=64, K=20.
//
// History:
//  R2: 1 row/thread, divergent row loads, c via SGPR. 153 us, 19% BW.
//  R6: asm 16-deep vmcnt MLP, divergent. 128 us (best). 64 lines/instr TA wall.
//  R7: one-shot 64KB LDS stage: 174 us. Coalesced (FETCH 125 MB) but bursty:
//      all waves drain at barrier, 0.4 us compute, block exit/re-ramp.
//  R8: single-wave persistent DMA dbuf: 377 us. TWO bugs: vmcnt(16) counted
//      the 5 output stores -> waited on freshly-issued loads (latency exposed
//      every tile); 1-wave blocks -> 2 waves/CU, no TLP. Staging numerics ok.
//  R9: LDS transpose + persistent MULTI-wave blocks + wave-independent
//      pipelines. 4 waves/block, each wave owns a private 16 KB tile buffer
//      (64 KB/block -> 2 blocks/CU -> 8 waves/CU). No __syncthreads at all.
//      Per tile: 16 global_load_lds (1 KB contiguous each, pre-swizzled
//      source), vmcnt(0), compute, plain stores. Eight staggered waves/CU
//      cover each other's drains; VALU demand ~17 us vs HBM floor ~37 us ->
//      self-balances into HBM-bound. WAR-safe single buffer: all ds_reads
//      are consumed before the next tile's DMA is issued (program order).

#define NPTS   1000000
#define DIM    64
#define KCL    20
#define BLOCK  256
#define WPB    4                 // waves per block
#define GRID   512               // 2 blocks/CU
#define NWAVES (GRID * WPB)      // 2048 persistent waves
#define NTILES (NPTS / 64)       // 15625 tiles of 64 rows, exact

typedef float f32x4 __attribute__((ext_vector_type(4)));

__global__ void csq_kernel(const float* __restrict__ c, float* __restrict__ csq)
{
    const int k = threadIdx.x;
    if (k < KCL) {
        const f32x4* c4 = (const f32x4*)c + k * (DIM / 4);
        float s = 0.f;
        #pragma unroll
        for (int m = 0; m < DIM / 4; ++m) {
            const f32x4 v = c4[m];
            s += v.x * v.x + v.y * v.y + v.z * v.z + v.w * v.w;
        }
        csq[k] = s;
    }
}

__global__ __launch_bounds__(BLOCK, 2) void cluster_q_kernel(
    const float* __restrict__ x,
    const float* __restrict__ c,
    const float* __restrict__ csq,
    float* __restrict__ out)
{
    // 4 wave-private tiles: 64 rows x 16 chunks of 16 B each = 16 KB/wave.
    __shared__ f32x4 sX[WPB][64][DIM / 4];

    const int tid  = threadIdx.x;
    const int wid  = tid >> 6;             // wave in block (buffer owner)
    const int lane = tid & 63;
    const int W    = blockIdx.x * WPB + wid;   // global wave id, 0..2047

    for (int t = W; t < NTILES; t += NWAVES) {
        const size_t rb = (size_t)t * 64;

        // ---- stage: 16 DMA instrs, each 1 KB contiguous (4 rows) ----
        // LDS linear dest (HW: uniform base + lane*16); source pre-swizzled
        // so LDS row r chunk p holds x[rb+r][p ^ (r&7)]  (verified R7/R8).
        #pragma unroll
        for (int i = 0; i < 16; ++i) {
            const int r  = i * 4 + (lane >> 4);
            const int ch = (lane & 15) ^ (r & 7);
            const float* gsrc = x + (rb + r) * DIM + ch * 4;
            __builtin_amdgcn_global_load_lds(
                (const __attribute__((address_space(1))) void*)gsrc,
                (__attribute__((address_space(3))) void*)&sX[wid][i * 4][0],
                16, 0, 0);
        }
        // Wait for THIS wave's 16 loads (old stores retired long ago).
        asm volatile("s_waitcnt vmcnt(0)" ::: "memory");
        __builtin_amdgcn_sched_barrier(0);

        // ---- compute: lane owns row rb+lane; c via uniform SGPR stream ----
        float acc[KCL];
        #pragma unroll
        for (int k = 0; k < KCL; ++k) acc[k] = 0.f;
        float xsq = 0.f;

        #pragma unroll
        for (int m = 0; m < DIM / 4; ++m) {
            const f32x4 xv = sX[wid][lane][m ^ (lane & 7)];   // de-swizzle
            xsq += xv.x * xv.x + xv.y * xv.y + xv.z * xv.z + xv.w * xv.w;
            #pragma unroll
            for (int k = 0; k < KCL; ++k) {
                acc[k] += xv.x * c[k * DIM + 4 * m + 0]
                        + xv.y * c[k * DIM + 4 * m + 1]
                        + xv.z * c[k * DIM + 4 * m + 2]
                        + xv.w * c[k * DIM + 4 * m + 3];
            }
        }

        // epilogue: d2 -> q -> normalize -> 5 float4 stores
        float s = 0.f;
        #pragma unroll
        for (int k = 0; k < KCL; ++k) {
            const float d2 = xsq + csq[k] - 2.0f * acc[k];   // csq: s_load
            const float qq = __builtin_amdgcn_rcpf(1.0f + d2);
            acc[k] = qq;
            s += qq;
        }
        const float inv = __builtin_amdgcn_rcpf(s);

        f32x4* o4 = (f32x4*)(out + (rb + lane) * KCL);
        #pragma unroll
        for (int k = 0; k < KCL; k += 4) {
            f32x4 v;
            v.x = acc[k + 0] * inv;
            v.y = acc[k + 1] * inv;
            v.z = acc[k + 2] * inv;
            v.w = acc[k + 3] * inv;
            o4[k / 4] = v;                 // plain store: L2 merges lines
        }
    }
}

extern "C" void kernel_launch(void* const* d_in, const int* in_sizes, int n_in,
                              void* d_out, int out_size, void* d_ws, size_t ws_size,
                              hipStream_t stream) {
    const float* x = (const float*)d_in[0];   // (N, D) fp32
    const float* c = (const float*)d_in[1];   // (K, D) fp32
    float* out = (float*)d_out;               // (N, K) fp32
    float* csq = (float*)d_ws;                // 20 floats of workspace

    csq_kernel<<<1, 64, 0, stream>>>(c, csq);
    cluster_q_kernel<<<GRID, BLOCK, 0, stream>>>(x, c, csq, out);
}

// Round 9
// 420.865 us; speedup vs baseline: 1.4907x; 1.0525x over previous
//
#include <hip/hip_runtime.h>

// cluster_layer: q[n,k] = (1/(1+||x_n - c_k||^2)) normalized over k  (alpha=1)
// N=1e6, D=64, K=20.
//
// History:
//  R2: row/thread, divergent loads, c via s_load stream. 153 us, 19% BW.
//  R6: + asm 16-deep vmcnt pipeline. 128 us (best). Divergence remains:
//      64 cache lines touched per load instr.
//  R7/R8/R9: DMA->LDS staging variants: 174/377/193 us. The DMA drain
//      serializes against compute regardless of wave structure; REJECT.
//  R10: remove ALL THREE suspects at once: no divergent vector loads, no
//      LDS staging, no in-loop scalar stream. (R11 = resubmit; container
//      infra failure, kernel never ran.)
//      Wave-iter = 4 rows. lane -> (g=lane>>4 row, d=lane&15 dim-chunk).
//      - x load: one dwordx4/lane/iter, 4 rows x 256 B = 8 lines (ideal).
//      - c PRELOADED per-lane: cv[k]=c[k][4d..4d+3] (80 VGPR). FMAs are
//        VGPR*VGPR; zero s_load in the loop.
//      - cross-lane reduce over the 16-lane group: ds_swizzle xor-butterfly
//        (1,2,4,8 -> offsets 0x041F,0x081F,0x101F,0x201F), DS pipe.
//      - epilogue redundant across the group (SIMT: free); (1+csq) folded
//        into pre-kernel so qq = rcp(fma(-2,cross,xsq+s1[k])).
//      - lane d<5 stores chunk d: 4 rows x 80 B = 320 B contiguous.

#define NPTS 1000000
#define DIM  64
#define KCL  20
#define BLOCK 256
#define ITERS 64                           // iters per wave
#define ROWS_PER_WAVE  (4 * ITERS)         // 256
#define ROWS_PER_BLOCK (4 * ROWS_PER_WAVE) // 1024
#define GRID ((NPTS + ROWS_PER_BLOCK - 1) / ROWS_PER_BLOCK)   // 977

typedef float f32x4 __attribute__((ext_vector_type(4)));

__global__ void csq_kernel(const float* __restrict__ c, float* __restrict__ s1)
{
    const int k = threadIdx.x;
    if (k < KCL) {
        const f32x4* c4 = (const f32x4*)c + k * (DIM / 4);
        float s = 0.f;
        #pragma unroll
        for (int m = 0; m < DIM / 4; ++m) {
            const f32x4 v = c4[m];
            s += v.x * v.x + v.y * v.y + v.z * v.z + v.w * v.w;
        }
        s1[k] = 1.0f + s;                  // fold the "+1" of 1/(1+d2)
    }
}

__device__ __forceinline__ float red16(float v)
{
    // sum across each 16-lane group (xor butterfly; stays within 16)
    v += __int_as_float(__builtin_amdgcn_ds_swizzle(__float_as_int(v), 0x041F));
    v += __int_as_float(__builtin_amdgcn_ds_swizzle(__float_as_int(v), 0x081F));
    v += __int_as_float(__builtin_amdgcn_ds_swizzle(__float_as_int(v), 0x101F));
    v += __int_as_float(__builtin_amdgcn_ds_swizzle(__float_as_int(v), 0x201F));
    return v;
}

__global__ __launch_bounds__(BLOCK, 4) void cluster_q_kernel(
    const float* __restrict__ x,
    const float* __restrict__ c,
    const float* __restrict__ s1,
    float* __restrict__ out)
{
    const int tid  = threadIdx.x;
    const int wid  = tid >> 6;
    const int lane = tid & 63;
    const int g    = lane >> 4;            // row within 4-row group
    const int d    = lane & 15;            // dim chunk (16 B)

    // per-lane cluster slice: cv[k] = c[k][4d..4d+3]  (80 VGPRs, coalesced)
    f32x4 cv[KCL];
    #pragma unroll
    for (int k = 0; k < KCL; ++k)
        cv[k] = *(const f32x4*)(c + k * DIM + d * 4);

    const int wrow0 = blockIdx.x * ROWS_PER_BLOCK + wid * ROWS_PER_WAVE;

    // first row for this lane (clamped for the tail block)
    int r0 = wrow0 + g;
    int rc0 = r0 < NPTS ? r0 : NPTS - 1;
    f32x4 xv = *(const f32x4*)(x + (size_t)rc0 * DIM + d * 4);

    for (int it = 0; it < ITERS; ++it) {
        const int r = wrow0 + it * 4 + g;

        // prefetch next iteration's chunk (coalesced, 8 lines/instr)
        const int itn = it + 1 < ITERS ? it + 1 : it;
        int rn = wrow0 + itn * 4 + g;
        if (rn >= NPTS) rn = NPTS - 1;
        const f32x4 xn = *(const f32x4*)(x + (size_t)rn * DIM + d * 4);

        // partial dots: pure VGPR FMAs
        float xsq = xv.x * xv.x + xv.y * xv.y + xv.z * xv.z + xv.w * xv.w;
        float acc[KCL];
        #pragma unroll
        for (int k = 0; k < KCL; ++k) {
            acc[k] = xv.x * cv[k].x + xv.y * cv[k].y
                   + xv.z * cv[k].z + xv.w * cv[k].w;
        }

        // reduce 21 values across the 16-lane group (independent chains)
        xsq = red16(xsq);
        #pragma unroll
        for (int k = 0; k < KCL; ++k) acc[k] = red16(acc[k]);

        // epilogue (all lanes of the group hold identical sums)
        float s = 0.f;
        #pragma unroll
        for (int k = 0; k < KCL; ++k) {
            // d2+1 = (xsq + 1 + csq[k]) - 2*cross
            const float b  = xsq + s1[k];                    // s1: hoisted s_load
            const float qq = __builtin_amdgcn_rcpf(__builtin_fmaf(-2.f, acc[k], b));
            acc[k] = qq;
            s += qq;
        }
        const float inv = __builtin_amdgcn_rcpf(s);

        // lane d<5 stores chunk d of its group's row: select q[4d..4d+3]
        const float o0 = d == 0 ? acc[0] : d == 1 ? acc[4] : d == 2 ? acc[8]
                       : d == 3 ? acc[12] : acc[16];
        const float o1 = d == 0 ? acc[1] : d == 1 ? acc[5] : d == 2 ? acc[9]
                       : d == 3 ? acc[13] : acc[17];
        const float o2 = d == 0 ? acc[2] : d == 1 ? acc[6] : d == 2 ? acc[10]
                       : d == 3 ? acc[14] : acc[18];
        const float o3 = d == 0 ? acc[3] : d == 1 ? acc[7] : d == 2 ? acc[11]
                       : d == 3 ? acc[15] : acc[19];

        if (d < 5 && r < NPTS) {
            f32x4 v;
            v.x = o0 * inv; v.y = o1 * inv; v.z = o2 * inv; v.w = o3 * inv;
            *(f32x4*)(out + (size_t)r * KCL + d * 4) = v;   // 320 B / 4 rows
        }

        xv = xn;
    }
}

extern "C" void kernel_launch(void* const* d_in, const int* in_sizes, int n_in,
                              void* d_out, int out_size, void* d_ws, size_t ws_size,
                              hipStream_t stream) {
    const float* x = (const float*)d_in[0];   // (N, D) fp32
    const float* c = (const float*)d_in[1];   // (K, D) fp32
    float* out = (float*)d_out;               // (N, K) fp32
    float* s1  = (float*)d_ws;                // 20 floats: 1 + ||c_k||^2

    csq_kernel<<<1, 64, 0, stream>>>(c, s1);
    cluster_q_kernel<<<GRID, BLOCK, 0, stream>>>(x, c, s1, out);
}

// Round 10
// 400.642 us; speedup vs baseline: 1.5659x; 1.0505x over previous
//
#include <hip/hip_runtime.h>

// cluster_layer: q[n,k] = (1/(1+||x_n - c_k||^2)) normalized over k  (alpha=1)
// N=1e6, D=64, K=20.
//
// History:
//  R2: row/thread, divergent loads, c via s_load. 153 us.
//  R6: + asm 16-deep vmcnt pipeline. ~128 us (best).
//  R7: one-shot LDS stage: 174 us (burst-drain-exit).
//  R8: dbuf DMA, WRONG vmcnt (ignored stores in the FIFO) + 1-wave blocks: 377.
//  R9: serial DMA->vmcnt(0)->compute: 193 us. CONVOY: identical waves all
//      drain together, CU alternates all-wait/all-compute, memory idles.
//  R10: lane-split + red16 butterfly: 175 us (cv spilled, DS reduce cost).
//  R11: R9 shell + per-wave DOUBLE BUFFER + STORE-AWARE counted vmcnt.
//      Per iter: stage(tile i) -> s_waitcnt vmcnt(21) -> compute+store(i-1).
//      21 = 5 stores(i-2) + 16 loads(i) issued after tile i-1's loads; vmcnt
//      retires loads AND stores in order, so the wait is exact. Every tile's
//      loads are issued one full compute phase (~2700 cy >> 900 cy latency)
//      ahead; waves never drain. 2-wave blocks, 64 KB LDS, 2 blocks/CU;
//      1024 waves x contiguous 15-16 tiles (15625 exact). No barriers.

#define NPTS 1000000
#define DIM  64
#define KCL  20
#define TPB  128                  // 2 waves per block
#define GRID 512                  // 1024 waves total
#define NTILES (NPTS / 64)        // 15625

typedef float f32x4 __attribute__((ext_vector_type(4)));

__global__ void csq_kernel(const float* __restrict__ c, float* __restrict__ s1)
{
    const int k = threadIdx.x;
    if (k < KCL) {
        const f32x4* c4 = (const f32x4*)c + k * (DIM / 4);
        float s = 0.f;
        #pragma unroll
        for (int m = 0; m < DIM / 4; ++m) {
            const f32x4 v = c4[m];
            s += v.x * v.x + v.y * v.y + v.z * v.z + v.w * v.w;
        }
        s1[k] = 1.0f + s;         // fold the "+1" of 1/(1+d2)
    }
}

__global__ __launch_bounds__(TPB, 1) void cluster_q_kernel(
    const float* __restrict__ x,
    const float* __restrict__ c,
    const float* __restrict__ s1,
    float* __restrict__ out)
{
    // [wave][buf][row][chunk]: 2*2*64*16*16B = 64 KB (static cap, 2 blocks/CU)
    __shared__ f32x4 sX[2][2][64][DIM / 4];

    const int tid  = threadIdx.x;
    const int wid  = tid >> 6;
    const int lane = tid & 63;
    const int W    = blockIdx.x * 2 + wid;            // 0..1023, wave-uniform

    // contiguous tile range: 15625 = 1024*15 + 265
    const int cnt   = 15 + (W < 265 ? 1 : 0);
    const int start = W * 15 + (W < 265 ? W : 265);

    // hoist s1 into registers (uniform -> s_loads, done once)
    float b1[KCL];
    #pragma unroll
    for (int k = 0; k < KCL; ++k) b1[k] = s1[k];

    // stage tile T into buffer B: 16 DMA instrs, each 1 KB contiguous.
    // LDS[r][p] <- x[T*64+r][p ^ (r&7)]  (verified swizzle pair, R7-R9)
#define STAGE(B, T)                                                           \
    {                                                                         \
        const size_t rb = (size_t)(T) * 64;                                   \
        _Pragma("unroll")                                                     \
        for (int i = 0; i < 16; ++i) {                                        \
            const int r  = i * 4 + (lane >> 4);                               \
            const int ch = (lane & 15) ^ (r & 7);                             \
            const float* gsrc = x + (rb + r) * DIM + ch * 4;                  \
            __builtin_amdgcn_global_load_lds(                                 \
                (const __attribute__((address_space(1))) void*)gsrc,          \
                (__attribute__((address_space(3))) void*)&sX[wid][B][i*4][0], \
                16, 0, 0);                                                    \
        }                                                                     \
    }

    // compute + store tile T from buffer B (lane owns row T*64+lane)
#define COMPUTE(B, T)                                                         \
    {                                                                         \
        float acc[KCL];                                                       \
        _Pragma("unroll")                                                     \
        for (int k = 0; k < KCL; ++k) acc[k] = 0.f;                           \
        float xsq = 0.f;                                                      \
        _Pragma("unroll")                                                     \
        for (int m = 0; m < DIM / 4; ++m) {                                   \
            const f32x4 xv = sX[wid][B][lane][m ^ (lane & 7)];                \
            xsq += xv.x * xv.x + xv.y * xv.y + xv.z * xv.z + xv.w * xv.w;     \
            _Pragma("unroll")                                                 \
            for (int k = 0; k < KCL; ++k) {                                   \
                acc[k] += xv.x * c[k * DIM + 4 * m + 0]                       \
                        + xv.y * c[k * DIM + 4 * m + 1]                       \
                        + xv.z * c[k * DIM + 4 * m + 2]                       \
                        + xv.w * c[k * DIM + 4 * m + 3];                      \
            }                                                                 \
        }                                                                     \
        float ssum = 0.f;                                                     \
        _Pragma("unroll")                                                     \
        for (int k = 0; k < KCL; ++k) {                                       \
            const float qq =                                                  \
                __builtin_amdgcn_rcpf(__builtin_fmaf(-2.f, acc[k], xsq + b1[k])); \
            acc[k] = qq;                                                      \
            ssum += qq;                                                       \
        }                                                                     \
        const float inv = __builtin_amdgcn_rcpf(ssum);                        \
        f32x4* o4 = (f32x4*)(out + ((size_t)(T) * 64 + lane) * KCL);          \
        _Pragma("unroll")                                                     \
        for (int k = 0; k < KCL; k += 4) {                                    \
            f32x4 v;                                                          \
            v.x = acc[k + 0] * inv; v.y = acc[k + 1] * inv;                   \
            v.z = acc[k + 2] * inv; v.w = acc[k + 3] * inv;                   \
            o4[k / 4] = v;                                                    \
        }                                                                     \
    }

    // ---- prologue: two tiles in flight ----
    STAGE(0, start)
    STAGE(1, start + 1)
    asm volatile("s_waitcnt vmcnt(16)" ::: "memory");   // tile start landed
    __builtin_amdgcn_sched_barrier(0);
    COMPUTE(0, start)                                   // 5 stores issued

    // ---- steady state: stage i, wait (5 stores + 16 loads)=21, compute i-1
    for (int i = 2; i < cnt; ++i) {
        const int buf = i & 1;                          // overwrite computed buf
        STAGE(buf, start + i)
        asm volatile("s_waitcnt vmcnt(21)" ::: "memory");
        __builtin_amdgcn_sched_barrier(0);
        COMPUTE(buf ^ 1, start + i - 1)
    }

    // ---- epilogue: last tile (only 5 stores after its loads) ----
    asm volatile("s_waitcnt vmcnt(5)" ::: "memory");
    __builtin_amdgcn_sched_barrier(0);
    COMPUTE((cnt - 1) & 1, start + cnt - 1)

#undef STAGE
#undef COMPUTE
}

extern "C" void kernel_launch(void* const* d_in, const int* in_sizes, int n_in,
                              void* d_out, int out_size, void* d_ws, size_t ws_size,
                              hipStream_t stream) {
    const float* x = (const float*)d_in[0];   // (N, D) fp32
    const float* c = (const float*)d_in[1];   // (K, D) fp32
    float* out = (float*)d_out;               // (N, K) fp32
    float* s1  = (float*)d_ws;                // 20 floats: 1 + ||c_k||^2

    csq_kernel<<<1, 64, 0, stream>>>(c, s1);
    cluster_q_kernel<<<GRID, TPB, 0, stream>>>(x, c, s1, out);
}

// Round 11
// 374.188 us; speedup vs baseline: 1.6766x; 1.0707x over previous
//
#include <hip/hip_runtime.h>

// cluster_layer: q[n,k] = (1/(1+||x_n - c_k||^2)) normalized over k  (alpha=1)
// N=1e6, D=64, K=20.
//
// History:
//  R2: row/thread, divergent loads, c via s_load. 153 us, 19% BW.
//  R6: + asm 16-deep vmcnt pipeline. 128 us (BEST). VGPR-heavy: 16 live
//      float4 + acc -> ~4 waves/SIMD max.
//  R7-R9,R11: DMA->LDS staging family: 174/377/193/~154 us. Even with
//      store-aware counted vmcnt dbuf (R11) it loses to R6. Path REJECTED.
//  R10: lane-split butterfly: 175 us (cv needed 80 VGPR under a 64-VGPR
//      allocation -> RA reloaded c in-loop; DS reduce cost).
//  R12: R6 with 2-group register rotation: issue chunks 0-7 (8 in flight),
//      consume 0-3 @ vmcnt(7..4), reissue dead group <- 8-11, consume 4-7
//      @ vmcnt(7..4), reissue <- 12-15, consume 8-11 @ vmcnt(7..4), consume
//      12-15 @ vmcnt(3..0). MLP stays 8-deep; xv registers 64 -> 32, total
//      ~70 -> 6-7 waves/SIMD possible (vs R6's ~4). Tests whether TLP was
//      the residual limit. All-volatile asm preserves load/wait order;
//      each consumer is data-chained to its wait ("+v").

#define NPTS 1000000
#define DIM  64
#define KCL  20
#define BLOCK 256

typedef float f32x4 __attribute__((ext_vector_type(4)));

__global__ __launch_bounds__(BLOCK, 4) void cluster_q_kernel(
    const float* __restrict__ x,
    const float* __restrict__ c,
    float* __restrict__ out)
{
    __shared__ float sCsq[KCL];

    // per-block csq (tiny: 20 lanes x 64 reads, c is L2-hot after block 0)
    if (threadIdx.x < KCL) {
        float s = 0.f;
        #pragma unroll
        for (int j = 0; j < DIM; ++j) {
            float v = c[threadIdx.x * DIM + j];
            s += v * v;
        }
        sCsq[threadIdx.x] = s;
    }
    __syncthreads();   // drains vmcnt/lgkmcnt for ALL threads before the asm

    const int row = blockIdx.x * BLOCK + threadIdx.x;
    if (row >= NPTS) return;

    const float* px = x + (size_t)row * DIM;   // 256 B per row, 16-B aligned

    // ---- group A = chunks 0-3, group B = chunks 4-7 (8 loads in flight) ----
    f32x4 a0, a1, a2, a3, b0, b1, b2, b3;
    asm volatile(
        "global_load_dwordx4 %0, %8, off\n\t"
        "global_load_dwordx4 %1, %8, off offset:16\n\t"
        "global_load_dwordx4 %2, %8, off offset:32\n\t"
        "global_load_dwordx4 %3, %8, off offset:48\n\t"
        "global_load_dwordx4 %4, %8, off offset:64\n\t"
        "global_load_dwordx4 %5, %8, off offset:80\n\t"
        "global_load_dwordx4 %6, %8, off offset:96\n\t"
        "global_load_dwordx4 %7, %8, off offset:112"
        : "=v"(a0), "=v"(a1), "=v"(a2), "=v"(a3),
          "=v"(b0), "=v"(b1), "=v"(b2), "=v"(b3)
        : "v"(px));

    float acc[KCL];
    #pragma unroll
    for (int k = 0; k < KCL; ++k) acc[k] = 0.f;
    float xsq = 0.f;

    // Consume chunk M once vmcnt <= VM (loads retire in order). The wait
    // asm reads+writes the chunk register, so every FMA on it is data-
    // dependent on the wait; volatile asm blocks keep mutual order.
#define STEP(M, XV, VM)                                               \
    asm volatile("s_waitcnt vmcnt(" #VM ")" : "+v"(XV));              \
    xsq += XV.x * XV.x + XV.y * XV.y + XV.z * XV.z + XV.w * XV.w;     \
    _Pragma("unroll")                                                 \
    for (int k = 0; k < KCL; ++k) {                                   \
        acc[k] += XV.x * c[k * DIM + 4 * (M) + 0]                     \
                + XV.y * c[k * DIM + 4 * (M) + 1]                     \
                + XV.z * c[k * DIM + 4 * (M) + 2]                     \
                + XV.w * c[k * DIM + 4 * (M) + 3];                    \
    }

    // consume chunks 0-3 (outstanding 8 -> 4)
    STEP(0, a0, 7)
    STEP(1, a1, 6)
    STEP(2, a2, 5)
    STEP(3, a3, 4)

    // reissue group A <- chunks 8-11 (outstanding 4 -> 8)
    asm volatile(
        "global_load_dwordx4 %0, %4, off offset:128\n\t"
        "global_load_dwordx4 %1, %4, off offset:144\n\t"
        "global_load_dwordx4 %2, %4, off offset:160\n\t"
        "global_load_dwordx4 %3, %4, off offset:176"
        : "=v"(a0), "=v"(a1), "=v"(a2), "=v"(a3)
        : "v"(px));

    // consume chunks 4-7 (8 -> 4)
    STEP(4, b0, 7)
    STEP(5, b1, 6)
    STEP(6, b2, 5)
    STEP(7, b3, 4)

    // reissue group B <- chunks 12-15 (4 -> 8)
    asm volatile(
        "global_load_dwordx4 %0, %4, off offset:192\n\t"
        "global_load_dwordx4 %1, %4, off offset:208\n\t"
        "global_load_dwordx4 %2, %4, off offset:224\n\t"
        "global_load_dwordx4 %3, %4, off offset:240"
        : "=v"(b0), "=v"(b1), "=v"(b2), "=v"(b3)
        : "v"(px));

    // consume chunks 8-11 (8 -> 4), then 12-15 (4 -> 0)
    STEP(8,  a0, 7)
    STEP(9,  a1, 6)
    STEP(10, a2, 5)
    STEP(11, a3, 4)
    STEP(12, b0, 3)
    STEP(13, b1, 2)
    STEP(14, b2, 1)
    STEP(15, b3, 0)
#undef STEP

    // epilogue: d2 -> q -> normalize -> 5 aligned float4 stores
    float s = 0.f;
    #pragma unroll
    for (int k = 0; k < KCL; ++k) {
        const float d2 = xsq + sCsq[k] - 2.0f * acc[k];
        const float qq = __builtin_amdgcn_rcpf(1.0f + d2);   // v_rcp_f32
        acc[k] = qq;
        s += qq;
    }
    const float inv = __builtin_amdgcn_rcpf(s);

    f32x4* o4 = (f32x4*)(out + (size_t)row * KCL);
    #pragma unroll
    for (int k = 0; k < KCL; k += 4) {
        f32x4 v;
        v.x = acc[k + 0] * inv;
        v.y = acc[k + 1] * inv;
        v.z = acc[k + 2] * inv;
        v.w = acc[k + 3] * inv;
        o4[k / 4] = v;            // plain store: L2 write-back merges lines
    }
}

extern "C" void kernel_launch(void* const* d_in, const int* in_sizes, int n_in,
                              void* d_out, int out_size, void* d_ws, size_t ws_size,
                              hipStream_t stream) {
    const float* x = (const float*)d_in[0];   // (N, D) fp32
    const float* c = (const float*)d_in[1];   // (K, D) fp32
    float* out = (float*)d_out;               // (N, K) fp32

    const int blocks = (NPTS + BLOCK - 1) / BLOCK;   // 3907
    cluster_q_kernel<<<blocks, BLOCK, 0, stream>>>(x, c, out);
}